// Round 14
// baseline (96.728 us; speedup 1.0000x reference)
//
#include <hip/hip_runtime.h>

#define DIM 128
#define NT 256
#define BUCK 32          // dst nodes per bucket == MFMA tile rows
#define PCH 8192         // edges per partition chunk
#define NBMAX 2048       // max buckets (n <= 65536)
#define BAT 256          // threads in fused aggregate (4 waves x 8 nodes)
#define CAPB 1024        // fixed csr slots per bucket (avg 512, max ~640; overflow-safe)
#define CONV_BLKS 512
#define WPACK_BLKS 16

typedef __attribute__((ext_vector_type(8))) short short8;
typedef __attribute__((ext_vector_type(8))) unsigned short ushort8;
typedef __attribute__((ext_vector_type(4))) float f32x4;
typedef __attribute__((ext_vector_type(2))) float f32x2;

static __device__ __forceinline__ unsigned short f32_to_bf16(float f) {
    union { float f; unsigned int u; } c; c.f = f;
    unsigned int u = c.u;
    u += 0x7FFFu + ((u >> 16) & 1u);   // RNE
    return (unsigned short)(u >> 16);
}

// ONE setup kernel, three independent block roles:
//  [0, PBLKS):            chunk-local partition into fixed-capacity bucket regions
//  [PBLKS, +CONV_BLKS):   x f32 -> bf16 table AND fp8(e4m3) gather table
//  [+, +WPACK_BLKS):      weight pack (MFMA B-fragment order) + combined bias
__global__ void setup_partition_kernel(const float* __restrict__ x, const int* __restrict__ ei,
                                       const float* __restrict__ w_self, const float* __restrict__ b_self,
                                       const float* __restrict__ w_neigh, const float* __restrict__ b_neigh,
                                       unsigned short* __restrict__ xb, unsigned int* __restrict__ xf8,
                                       unsigned short* __restrict__ w_swz,
                                       float* __restrict__ bias, int* __restrict__ gcur,
                                       int* __restrict__ ovfc, unsigned int* __restrict__ csr,
                                       unsigned int* __restrict__ ovf,
                                       int n4, int E, int NB, int PBLKS) {
    int b = blockIdx.x, t = threadIdx.x;
    if (b < PBLKS) {
        __shared__ int hist[NBMAX];
        __shared__ int base[NBMAX];
        __shared__ int avail[NBMAX];
        __shared__ int obase[NBMAX];
        __shared__ int lcur[NBMAX];
        int cbase = b * PCH;
        int cend = min(E, cbase + PCH);
        for (int i = t; i < NB; i += NT) { hist[i] = 0; lcur[i] = 0; }
        __syncthreads();
        for (int e = cbase + t; e < cend; e += NT)
            atomicAdd(&hist[ei[E + e] >> 5], 1);
        __syncthreads();
        for (int bk = t; bk < NB; bk += NT) {
            int c = hist[bk];
            if (c) {
                int r = atomicAdd(&gcur[bk], c);
                int av = (r < CAPB) ? min(c, CAPB - r) : 0;
                base[bk] = r;
                avail[bk] = av;
                obase[bk] = (c > av) ? atomicAdd(ovfc, c - av) : 0;
            }
        }
        __syncthreads();
        for (int e = cbase + t; e < cend; e += NT) {
            unsigned int src = (unsigned int)ei[e];
            unsigned int dst = (unsigned int)ei[E + e];
            int bk = (int)(dst >> 5);
            int idx = atomicAdd(&lcur[bk], 1);
            unsigned int pk = (dst << 16) | src;
            if (idx < avail[bk]) csr[(size_t)bk * CAPB + base[bk] + idx] = pk;
            else ovf[obase[bk] + idx - avail[bk]] = pk;
        }
    } else if (b < PBLKS + CONV_BLKS) {
        for (int g = (b - PBLKS) * NT + t; g < n4; g += CONV_BLKS * NT) {
            float4 v = reinterpret_cast<const float4*>(x)[g];
            ushort4 s = make_ushort4(f32_to_bf16(v.x), f32_to_bf16(v.y),
                                     f32_to_bf16(v.z), f32_to_bf16(v.w));
            reinterpret_cast<ushort4*>(xb)[g] = s;
            int p = __builtin_amdgcn_cvt_pk_fp8_f32(v.x, v.y, 0, false);   // bytes 0,1
            p = __builtin_amdgcn_cvt_pk_fp8_f32(v.z, v.w, p, true);        // bytes 2,3
            xf8[g] = (unsigned int)p;
        }
    } else {
        int g = (b - PBLKS - CONV_BLKS) * NT + t;   // 4096 slots
        if (g < 128) bias[g] = b_self[g] + b_neigh[g];
        if (g >= 64 * 64) return;
        int f = g >> 6, l = g & 63;
        int ks = f >> 3, nf = f & 7;
        int j = nf * 16 + (l & 15);
        int kbase = ks * 32 + ((l >> 4) << 3);
#pragma unroll
        for (int e = 0; e < 8; ++e) {
            int k = kbase + e;
            float v = (k < 128) ? w_self[(size_t)j * 128 + k]
                                : w_neigh[(size_t)j * 128 + (k - 128)];
            w_swz[((size_t)g << 3) + e] = f32_to_bf16(v);
        }
    }
}

// FUSED aggregate + finalize. One block per bucket (= 32 output rows), 4 waves.
// fp8 gather: NODE-PAIR loop issues 8 quad-gathers (32 edges, 2 nodes) before
// decoding — 2x memory-level parallelism vs per-node. Packed f32x2 accumulate
// (v_pk_add_f32). Mean -> bf16 A-tile; 4-wave MFMA epilogue.
__global__ void __launch_bounds__(BAT)
fused_aggregate_kernel(const unsigned short* __restrict__ xb,
                       const unsigned int* __restrict__ xf8,
                       const int* __restrict__ gcur,
                       const int* __restrict__ ovfc,
                       const unsigned int* __restrict__ csr,
                       const unsigned int* __restrict__ ovf,
                       const unsigned short* __restrict__ w_swz,
                       const float* __restrict__ bias,
                       float* __restrict__ out, int n) {
    __shared__ unsigned short srt[CAPB];       // sorted src ids (2KB)
    __shared__ unsigned short xm[BUCK][264];   // [x(128) | mean(128)] bf16 (16.9KB)
    __shared__ int bin[BUCK];
    __shared__ int boff_s[BUCK + 1];
    __shared__ int cur[BUCK];

    int tid = threadIdx.x, wid = tid >> 6, lane = tid & 63;
    int grp = lane >> 4, j = lane & 15;     // 4 groups of 16 lanes
    int b0 = blockIdx.x;
    int bsize = min(gcur[b0], CAPB);
    int ovfn = ovfc[0];
    const unsigned int* my = csr + (size_t)b0 * CAPB;
    int gbase = b0 * BUCK;
    const uint2* x8 = reinterpret_cast<const uint2*>(xf8);   // 16 uint2 per fp8 row

    // Stage x rows into A-tile x-part (coalesced, bf16).
    for (int fi = tid; fi < BUCK * 16; fi += BAT) {
        int row = fi >> 4, c = fi & 15;
        int grow = gbase + row;
        ushort8 s = (ushort8)0;
        if (grow < n) s = reinterpret_cast<const ushort8*>(xb + (size_t)grow * DIM)[c];
        *reinterpret_cast<ushort8*>(&xm[row][c * 8]) = s;
    }

    if (bsize > 0) {
        // ---- counting sort by local dst (32 bins) ----
        for (int i = tid; i < BUCK; i += BAT) bin[i] = 0;
        __syncthreads();
        for (int i = tid; i < bsize; i += BAT)
            atomicAdd(&bin[(my[i] >> 16) & 31], 1);
        __syncthreads();
        if (wid == 0) {   // wave-0 shuffle scan of 32 bins
            int v = (lane < BUCK) ? bin[lane] : 0;
            int s = v;
            for (int d = 1; d < BUCK; d <<= 1) {
                int u = __shfl_up(s, d, 64);
                if (lane >= d) s += u;
            }
            if (lane < BUCK) {
                boff_s[lane] = s - v;
                cur[lane] = s - v;
                if (lane == BUCK - 1) boff_s[BUCK] = s;
            }
        }
        __syncthreads();
        for (int i = tid; i < bsize; i += BAT) {
            unsigned int p = my[i];
            int d = (p >> 16) & 31;
            srt[atomicAdd(&cur[d], 1)] = (unsigned short)(p & 0xFFFFu);
        }
        __syncthreads();

        // ---- node-pair gather: 8 loads (32 edges) in flight ----
#pragma unroll
        for (int ii = 0; ii < 8; ii += 2) {
            int nd0 = wid * 8 + ii, nd1 = nd0 + 1;
            int s0 = boff_s[nd0], end0 = boff_s[nd0 + 1];
            int s1 = boff_s[nd1], end1 = boff_s[nd1 + 1];
            f32x2 ac0[4], ac1[4];
#pragma unroll
            for (int k = 0; k < 4; ++k) { ac0[k] = (f32x2){0.f, 0.f}; ac1[k] = (f32x2){0.f, 0.f}; }
            int iters = max((end0 - s0 + 15) >> 4, (end1 - s1 + 15) >> 4);
            int e0 = s0, e1 = s1;
            for (int it = 0; it < iters; ++it, e0 += 16, e1 += 16) {
                uint2 v0[4], v1[4];
#pragma unroll
                for (int q = 0; q < 4; ++q) {
                    int i0 = e0 + q * 4 + grp;
                    bool ok0 = i0 < end0;
                    uint2 t0 = x8[(size_t)srt[ok0 ? i0 : s0] * 16 + j];
                    v0[q] = ok0 ? t0 : make_uint2(0u, 0u);
                    int i1 = e1 + q * 4 + grp;
                    bool ok1 = i1 < end1;
                    uint2 t1 = x8[(size_t)srt[ok1 ? i1 : s1] * 16 + j];
                    v1[q] = ok1 ? t1 : make_uint2(0u, 0u);
                }
#pragma unroll
                for (int q = 0; q < 4; ++q) {
                    ac0[0] += __builtin_amdgcn_cvt_pk_f32_fp8(v0[q].x, false);
                    ac0[1] += __builtin_amdgcn_cvt_pk_f32_fp8(v0[q].x, true);
                    ac0[2] += __builtin_amdgcn_cvt_pk_f32_fp8(v0[q].y, false);
                    ac0[3] += __builtin_amdgcn_cvt_pk_f32_fp8(v0[q].y, true);
                    ac1[0] += __builtin_amdgcn_cvt_pk_f32_fp8(v1[q].x, false);
                    ac1[1] += __builtin_amdgcn_cvt_pk_f32_fp8(v1[q].x, true);
                    ac1[2] += __builtin_amdgcn_cvt_pk_f32_fp8(v1[q].y, false);
                    ac1[3] += __builtin_amdgcn_cvt_pk_f32_fp8(v1[q].y, true);
                }
            }
            int dg0 = end0 - s0, dg1 = end1 - s1;
            // Overflow edges (normally ovfn == 0).
            for (int o = 0; o < ovfn; ++o) {
                unsigned int p = ovf[o];
                int pd = (int)(p >> 16);
                if (pd == gbase + nd0 || pd == gbase + nd1) {
                    uint2 tv = x8[(size_t)(p & 0xFFFFu) * 16 + j];
                    f32x2* ac = (pd == gbase + nd0) ? ac0 : ac1;
                    ac[0] += __builtin_amdgcn_cvt_pk_f32_fp8(tv.x, false);
                    ac[1] += __builtin_amdgcn_cvt_pk_f32_fp8(tv.x, true);
                    ac[2] += __builtin_amdgcn_cvt_pk_f32_fp8(tv.y, false);
                    ac[3] += __builtin_amdgcn_cvt_pk_f32_fp8(tv.y, true);
                    if (pd == gbase + nd0) ++dg0; else ++dg1;
                }
            }
            // cross-group reduce + write, per node of the pair.
#pragma unroll
            for (int half = 0; half < 2; ++half) {
                f32x2* ac = half ? ac1 : ac0;
                int nd = half ? nd1 : nd0;
                int deg = half ? dg1 : dg0;
                float t[8];
#pragma unroll
                for (int k = 0; k < 4; ++k) { t[2 * k] = ac[k].x; t[2 * k + 1] = ac[k].y; }
#pragma unroll
                for (int k = 0; k < 8; ++k) {
                    t[k] += __shfl_xor(t[k], 16);
                    t[k] += __shfl_xor(t[k], 32);
                }
                float inv = deg > 0 ? 1.0f / (float)deg : 0.f;
                if (grp == 0) {
                    ushort8 m = (ushort8)0;
#pragma unroll
                    for (int k = 0; k < 8; ++k) m[k] = f32_to_bf16(t[k] * inv);
                    *reinterpret_cast<ushort8*>(&xm[nd][128 + j * 8]) = m;
                }
            }
        }
    } else {
        // Empty bucket: zero the mean half of the A-tile.
        if (grp == 0) {
            ushort8 z = (ushort8)0;
#pragma unroll
            for (int i = 0; i < 8; ++i)
                *reinterpret_cast<ushort8*>(&xm[wid * 8 + i][128 + j * 8]) = z;
        }
    }
    __syncthreads();

    // ---- MFMA epilogue: 4 waves, wave = 16-row x 64-col quadrant ----
    int rg = wid >> 1, ch = wid & 1;
    int arow = rg * 16 + (lane & 15);
    int koff = (lane >> 4) << 3;

    f32x4 acc[4];
#pragma unroll
    for (int nf = 0; nf < 4; ++nf) acc[nf] = (f32x4){0.f, 0.f, 0.f, 0.f};

#pragma unroll
    for (int ks = 0; ks < 8; ++ks) {
        short8 a = *reinterpret_cast<const short8*>(&xm[arow][ks * 32 + koff]);
#pragma unroll
        for (int nf = 0; nf < 4; ++nf) {
            int f = ks * 8 + ch * 4 + nf;
            short8 b = *reinterpret_cast<const short8*>(w_swz + (((size_t)f * 64 + lane) << 3));
            acc[nf] = __builtin_amdgcn_mfma_f32_16x16x32_bf16(a, b, acc[nf], 0, 0, 0);
        }
    }

    int crow0 = rg * 16 + ((lane >> 4) << 2);
#pragma unroll
    for (int nf = 0; nf < 4; ++nf) {
        int col = (ch * 4 + nf) * 16 + (lane & 15);
        float bs = bias[col];
#pragma unroll
        for (int r = 0; r < 4; ++r) {
            int grow = gbase + crow0 + r;
            if (grow < n) out[(size_t)grow * DIM + col] = acc[nf][r] + bs;
        }
    }
}

extern "C" void kernel_launch(void* const* d_in, const int* in_sizes, int n_in,
                              void* d_out, int out_size, void* d_ws, size_t ws_size,
                              hipStream_t stream) {
    const float* x       = (const float*)d_in[0];
    const int*   ei      = (const int*)d_in[1];
    const float* w_self  = (const float*)d_in[2];
    const float* b_self  = (const float*)d_in[3];
    const float* w_neigh = (const float*)d_in[4];
    const float* b_neigh = (const float*)d_in[5];
    float* out = (float*)d_out;

    int n = in_sizes[0] / DIM;
    int E = in_sizes[1] / 2;
    int NB = (n + BUCK - 1) / BUCK;   // 1563 for n=50000; requires NB <= NBMAX

    // ws: gcur[NBMAX] | ovfc[4] | csr uint[NB*CAPB] (~6.4MB) | ovf uint[E] (~3.2MB) |
    //     (align16) w_swz bf16[32768] | bias f32[128] | x_bf bf16[n*128] (~12.8MB) |
    //     x_fp8 uint[n*32] (~6.4MB)
    int* gcur = (int*)d_ws;
    int* ovfc = gcur + NBMAX;
    unsigned int* csr = (unsigned int*)(ovfc + 4);
    unsigned int* ovf = csr + (size_t)NB * CAPB;
    unsigned short* w_swz = (unsigned short*)(((uintptr_t)(ovf + E) + 15) & ~(uintptr_t)15);
    float* bias = (float*)(w_swz + 64 * 64 * 8);
    unsigned short* x_bf = (unsigned short*)(bias + 128);
    unsigned int* x_fp8 = (unsigned int*)(x_bf + (size_t)n * DIM);

    hipMemsetAsync(gcur, 0, (NBMAX + 4) * sizeof(int), stream);

    int n4 = n * DIM / 4;
    int PBLKS = (E + PCH - 1) / PCH;   // 98
    setup_partition_kernel<<<PBLKS + CONV_BLKS + WPACK_BLKS, NT, 0, stream>>>(
        x, ei, w_self, b_self, w_neigh, b_neigh, x_bf, x_fp8, w_swz, bias,
        gcur, ovfc, csr, ovf, n4, E, NB, PBLKS);

    fused_aggregate_kernel<<<NB, BAT, 0, stream>>>(x_bf, x_fp8, gcur, ovfc, csr, ovf,
                                                   w_swz, bias, out, n);
}

// Round 15
// 74.127 us; speedup vs baseline: 1.3049x; 1.3049x over previous
//
#include <hip/hip_runtime.h>

#define DIM 128
#define NT 256
#define BUCK 32          // dst nodes per bucket == MFMA tile rows
#define PCH 4096         // edges per partition chunk
#define NBMAX 2048       // max buckets (n <= 65536)
#define BAT 256          // threads in fused aggregate (4 waves x 8 nodes)
#define CAPB 1024        // fixed csr slots per bucket (avg 512, max ~640; overflow-safe)
#define CONV_BLKS 512
#define WPACK_BLKS 16

typedef __attribute__((ext_vector_type(8))) short short8;
typedef __attribute__((ext_vector_type(8))) unsigned short ushort8;
typedef __attribute__((ext_vector_type(4))) float f32x4;
typedef __attribute__((ext_vector_type(2))) float f32x2;

static __device__ __forceinline__ unsigned short f32_to_bf16(float f) {
    union { float f; unsigned int u; } c; c.f = f;
    unsigned int u = c.u;
    u += 0x7FFFu + ((u >> 16) & 1u);   // RNE
    return (unsigned short)(u >> 16);
}

// ONE setup kernel, three independent block roles:
//  [0, PBLKS):            chunk-local partition into fixed-capacity bucket regions
//  [PBLKS, +CONV_BLKS):   x f32 -> bf16 table AND fp8(e4m3) gather table
//  [+, +WPACK_BLKS):      weight pack (MFMA B-fragment order) + combined bias
__global__ void setup_partition_kernel(const float* __restrict__ x, const int* __restrict__ ei,
                                       const float* __restrict__ w_self, const float* __restrict__ b_self,
                                       const float* __restrict__ w_neigh, const float* __restrict__ b_neigh,
                                       unsigned short* __restrict__ xb, unsigned int* __restrict__ xf8,
                                       unsigned short* __restrict__ w_swz,
                                       float* __restrict__ bias, int* __restrict__ gcur,
                                       int* __restrict__ ovfc, unsigned int* __restrict__ csr,
                                       unsigned int* __restrict__ ovf,
                                       int n4, int E, int NB, int PBLKS) {
    int b = blockIdx.x, t = threadIdx.x;
    if (b < PBLKS) {
        __shared__ int hist[NBMAX];
        __shared__ int base[NBMAX];
        __shared__ int avail[NBMAX];
        __shared__ int obase[NBMAX];
        __shared__ int lcur[NBMAX];
        int cbase = b * PCH;
        int cend = min(E, cbase + PCH);
        for (int i = t; i < NB; i += NT) { hist[i] = 0; lcur[i] = 0; }
        __syncthreads();
        for (int e = cbase + t; e < cend; e += NT)
            atomicAdd(&hist[ei[E + e] >> 5], 1);
        __syncthreads();
        for (int bk = t; bk < NB; bk += NT) {
            int c = hist[bk];
            if (c) {
                int r = atomicAdd(&gcur[bk], c);
                int av = (r < CAPB) ? min(c, CAPB - r) : 0;
                base[bk] = r;
                avail[bk] = av;
                obase[bk] = (c > av) ? atomicAdd(ovfc, c - av) : 0;
            }
        }
        __syncthreads();
        for (int e = cbase + t; e < cend; e += NT) {
            unsigned int src = (unsigned int)ei[e];
            unsigned int dst = (unsigned int)ei[E + e];
            int bk = (int)(dst >> 5);
            int idx = atomicAdd(&lcur[bk], 1);
            unsigned int pk = (dst << 16) | src;
            if (idx < avail[bk]) csr[(size_t)bk * CAPB + base[bk] + idx] = pk;
            else ovf[obase[bk] + idx - avail[bk]] = pk;
        }
    } else if (b < PBLKS + CONV_BLKS) {
        for (int g = (b - PBLKS) * NT + t; g < n4; g += CONV_BLKS * NT) {
            float4 v = reinterpret_cast<const float4*>(x)[g];
            ushort4 s = make_ushort4(f32_to_bf16(v.x), f32_to_bf16(v.y),
                                     f32_to_bf16(v.z), f32_to_bf16(v.w));
            reinterpret_cast<ushort4*>(xb)[g] = s;
            int p = __builtin_amdgcn_cvt_pk_fp8_f32(v.x, v.y, 0, false);   // bytes 0,1
            p = __builtin_amdgcn_cvt_pk_fp8_f32(v.z, v.w, p, true);        // bytes 2,3
            xf8[g] = (unsigned int)p;
        }
    } else {
        int g = (b - PBLKS - CONV_BLKS) * NT + t;   // 4096 slots
        if (g < 128) bias[g] = b_self[g] + b_neigh[g];
        if (g >= 64 * 64) return;
        int f = g >> 6, l = g & 63;
        int ks = f >> 3, nf = f & 7;
        int j = nf * 16 + (l & 15);
        int kbase = ks * 32 + ((l >> 4) << 3);
#pragma unroll
        for (int e = 0; e < 8; ++e) {
            int k = kbase + e;
            float v = (k < 128) ? w_self[(size_t)j * 128 + k]
                                : w_neigh[(size_t)j * 128 + (k - 128)];
            w_swz[((size_t)g << 3) + e] = f32_to_bf16(v);
        }
    }
}

// FUSED aggregate + finalize. One block per bucket (= 32 output rows), 4 waves.
// fp8 gather, node-PAIR pipelined with scalar load buffers (no arrays, no outer
// unroll -> no spill): up to 8 quad-loads (32 edges) in flight. Wave-uniform
// guards. Packed f32x2 accumulate; mean -> bf16 A-tile; 4-wave MFMA epilogue.
__global__ void __launch_bounds__(BAT)
fused_aggregate_kernel(const unsigned short* __restrict__ xb,
                       const unsigned int* __restrict__ xf8,
                       const int* __restrict__ gcur,
                       const int* __restrict__ ovfc,
                       const unsigned int* __restrict__ csr,
                       const unsigned int* __restrict__ ovf,
                       const unsigned short* __restrict__ w_swz,
                       const float* __restrict__ bias,
                       float* __restrict__ out, int n) {
    __shared__ unsigned short srt[CAPB];       // sorted src ids (2KB)
    __shared__ unsigned short xm[BUCK][264];   // [x(128) | mean(128)] bf16 (16.9KB)
    __shared__ int bin[BUCK];
    __shared__ int boff_s[BUCK + 1];
    __shared__ int cur[BUCK];

    int tid = threadIdx.x, wid = tid >> 6, lane = tid & 63;
    int grp = lane >> 4, j = lane & 15;     // 4 groups of 16 lanes
    int b0 = blockIdx.x;
    int bsize = min(gcur[b0], CAPB);
    int ovfn = ovfc[0];
    const unsigned int* my = csr + (size_t)b0 * CAPB;
    int gbase = b0 * BUCK;
    const uint2* x8 = reinterpret_cast<const uint2*>(xf8);   // 16 uint2 per fp8 row

    // Stage x rows into A-tile x-part (coalesced, bf16).
    for (int fi = tid; fi < BUCK * 16; fi += BAT) {
        int row = fi >> 4, c = fi & 15;
        int grow = gbase + row;
        ushort8 s = (ushort8)0;
        if (grow < n) s = reinterpret_cast<const ushort8*>(xb + (size_t)grow * DIM)[c];
        *reinterpret_cast<ushort8*>(&xm[row][c * 8]) = s;
    }

    // ---- counting sort by local dst (32 bins) ----
    for (int i = tid; i < BUCK; i += BAT) bin[i] = 0;
    __syncthreads();
    for (int i = tid; i < bsize; i += BAT)
        atomicAdd(&bin[(my[i] >> 16) & 31], 1);
    __syncthreads();
    if (wid == 0) {   // wave-0 shuffle scan of 32 bins
        int v = (lane < BUCK) ? bin[lane] : 0;
        int s = v;
        for (int d = 1; d < BUCK; d <<= 1) {
            int u = __shfl_up(s, d, 64);
            if (lane >= d) s += u;
        }
        if (lane < BUCK) {
            boff_s[lane] = s - v;
            cur[lane] = s - v;
            if (lane == BUCK - 1) boff_s[BUCK] = s;
        }
    }
    __syncthreads();
    for (int i = tid; i < bsize; i += BAT) {
        unsigned int p = my[i];
        int d = (p >> 16) & 31;
        srt[atomicAdd(&cur[d], 1)] = (unsigned short)(p & 0xFFFFu);
    }
    __syncthreads();

    // ---- node-pair gather: up to 8 quad-loads (32 edges) in flight ----
    for (int ii = 0; ii < 8; ii += 2) {      // NOT unrolled (keeps live state small)
        int nd0 = wid * 8 + ii, nd1 = nd0 + 1;
        int s0 = boff_s[nd0], end0 = boff_s[nd0 + 1];
        int s1 = boff_s[nd1], end1 = boff_s[nd1 + 1];
        f32x2 c00 = {0.f, 0.f}, c01 = {0.f, 0.f}, c02 = {0.f, 0.f}, c03 = {0.f, 0.f};
        f32x2 c10 = {0.f, 0.f}, c11 = {0.f, 0.f}, c12 = {0.f, 0.f}, c13 = {0.f, 0.f};
        int e0 = s0, e1 = s1;
        while (e0 < end0 || e1 < end1) {     // wave-uniform condition
            bool h0 = e0 < end0, h1 = e1 < end1;
            uint2 a0, a1, a2, a3, b0, b1, b2, b3;
            if (h0) {                        // wave-uniform branch
                int i0 = e0 + grp, i1 = e0 + 4 + grp, i2 = e0 + 8 + grp, i3 = e0 + 12 + grp;
                bool k0 = i0 < end0, k1 = i1 < end0, k2 = i2 < end0, k3 = i3 < end0;
                a0 = x8[(size_t)srt[k0 ? i0 : s0] * 16 + j];
                a1 = x8[(size_t)srt[k1 ? i1 : s0] * 16 + j];
                a2 = x8[(size_t)srt[k2 ? i2 : s0] * 16 + j];
                a3 = x8[(size_t)srt[k3 ? i3 : s0] * 16 + j];
                if (!k0) a0 = make_uint2(0u, 0u);
                if (!k1) a1 = make_uint2(0u, 0u);
                if (!k2) a2 = make_uint2(0u, 0u);
                if (!k3) a3 = make_uint2(0u, 0u);
            }
            if (h1) {
                int i0 = e1 + grp, i1 = e1 + 4 + grp, i2 = e1 + 8 + grp, i3 = e1 + 12 + grp;
                bool k0 = i0 < end1, k1 = i1 < end1, k2 = i2 < end1, k3 = i3 < end1;
                b0 = x8[(size_t)srt[k0 ? i0 : s1] * 16 + j];
                b1 = x8[(size_t)srt[k1 ? i1 : s1] * 16 + j];
                b2 = x8[(size_t)srt[k2 ? i2 : s1] * 16 + j];
                b3 = x8[(size_t)srt[k3 ? i3 : s1] * 16 + j];
                if (!k0) b0 = make_uint2(0u, 0u);
                if (!k1) b1 = make_uint2(0u, 0u);
                if (!k2) b2 = make_uint2(0u, 0u);
                if (!k3) b3 = make_uint2(0u, 0u);
            }
            if (h0) {
                c00 += __builtin_amdgcn_cvt_pk_f32_fp8(a0.x, false);
                c01 += __builtin_amdgcn_cvt_pk_f32_fp8(a0.x, true);
                c02 += __builtin_amdgcn_cvt_pk_f32_fp8(a0.y, false);
                c03 += __builtin_amdgcn_cvt_pk_f32_fp8(a0.y, true);
                c00 += __builtin_amdgcn_cvt_pk_f32_fp8(a1.x, false);
                c01 += __builtin_amdgcn_cvt_pk_f32_fp8(a1.x, true);
                c02 += __builtin_amdgcn_cvt_pk_f32_fp8(a1.y, false);
                c03 += __builtin_amdgcn_cvt_pk_f32_fp8(a1.y, true);
                c00 += __builtin_amdgcn_cvt_pk_f32_fp8(a2.x, false);
                c01 += __builtin_amdgcn_cvt_pk_f32_fp8(a2.x, true);
                c02 += __builtin_amdgcn_cvt_pk_f32_fp8(a2.y, false);
                c03 += __builtin_amdgcn_cvt_pk_f32_fp8(a2.y, true);
                c00 += __builtin_amdgcn_cvt_pk_f32_fp8(a3.x, false);
                c01 += __builtin_amdgcn_cvt_pk_f32_fp8(a3.x, true);
                c02 += __builtin_amdgcn_cvt_pk_f32_fp8(a3.y, false);
                c03 += __builtin_amdgcn_cvt_pk_f32_fp8(a3.y, true);
                e0 += 16;
            }
            if (h1) {
                c10 += __builtin_amdgcn_cvt_pk_f32_fp8(b0.x, false);
                c11 += __builtin_amdgcn_cvt_pk_f32_fp8(b0.x, true);
                c12 += __builtin_amdgcn_cvt_pk_f32_fp8(b0.y, false);
                c13 += __builtin_amdgcn_cvt_pk_f32_fp8(b0.y, true);
                c10 += __builtin_amdgcn_cvt_pk_f32_fp8(b1.x, false);
                c11 += __builtin_amdgcn_cvt_pk_f32_fp8(b1.x, true);
                c12 += __builtin_amdgcn_cvt_pk_f32_fp8(b1.y, false);
                c13 += __builtin_amdgcn_cvt_pk_f32_fp8(b1.y, true);
                c10 += __builtin_amdgcn_cvt_pk_f32_fp8(b2.x, false);
                c11 += __builtin_amdgcn_cvt_pk_f32_fp8(b2.x, true);
                c12 += __builtin_amdgcn_cvt_pk_f32_fp8(b2.y, false);
                c13 += __builtin_amdgcn_cvt_pk_f32_fp8(b2.y, true);
                c10 += __builtin_amdgcn_cvt_pk_f32_fp8(b3.x, false);
                c11 += __builtin_amdgcn_cvt_pk_f32_fp8(b3.x, true);
                c12 += __builtin_amdgcn_cvt_pk_f32_fp8(b3.y, false);
                c13 += __builtin_amdgcn_cvt_pk_f32_fp8(b3.y, true);
                e1 += 16;
            }
        }
        int dg0 = end0 - s0, dg1 = end1 - s1;
        // Overflow edges (normally ovfn == 0).
        for (int o = 0; o < ovfn; ++o) {
            unsigned int p = ovf[o];
            int pd = (int)(p >> 16);
            if (pd == gbase + nd0 || pd == gbase + nd1) {
                uint2 tv = x8[(size_t)(p & 0xFFFFu) * 16 + j];
                f32x2 d0 = __builtin_amdgcn_cvt_pk_f32_fp8(tv.x, false);
                f32x2 d1 = __builtin_amdgcn_cvt_pk_f32_fp8(tv.x, true);
                f32x2 d2 = __builtin_amdgcn_cvt_pk_f32_fp8(tv.y, false);
                f32x2 d3 = __builtin_amdgcn_cvt_pk_f32_fp8(tv.y, true);
                if (pd == gbase + nd0) { c00 += d0; c01 += d1; c02 += d2; c03 += d3; ++dg0; }
                else                   { c10 += d0; c11 += d1; c12 += d2; c13 += d3; ++dg1; }
            }
        }
        // cross-group reduce + write, per node of the pair.
        {
            float t0[8] = {c00.x, c00.y, c01.x, c01.y, c02.x, c02.y, c03.x, c03.y};
#pragma unroll
            for (int k = 0; k < 8; ++k) {
                t0[k] += __shfl_xor(t0[k], 16);
                t0[k] += __shfl_xor(t0[k], 32);
            }
            float inv = dg0 > 0 ? 1.0f / (float)dg0 : 0.f;
            if (grp == 0) {
                ushort8 m = (ushort8)0;
#pragma unroll
                for (int k = 0; k < 8; ++k) m[k] = f32_to_bf16(t0[k] * inv);
                *reinterpret_cast<ushort8*>(&xm[nd0][128 + j * 8]) = m;
            }
        }
        {
            float t1[8] = {c10.x, c10.y, c11.x, c11.y, c12.x, c12.y, c13.x, c13.y};
#pragma unroll
            for (int k = 0; k < 8; ++k) {
                t1[k] += __shfl_xor(t1[k], 16);
                t1[k] += __shfl_xor(t1[k], 32);
            }
            float inv = dg1 > 0 ? 1.0f / (float)dg1 : 0.f;
            if (grp == 0) {
                ushort8 m = (ushort8)0;
#pragma unroll
                for (int k = 0; k < 8; ++k) m[k] = f32_to_bf16(t1[k] * inv);
                *reinterpret_cast<ushort8*>(&xm[nd1][128 + j * 8]) = m;
            }
        }
    }
    __syncthreads();

    // ---- MFMA epilogue: 4 waves, wave = 16-row x 64-col quadrant ----
    int rg = wid >> 1, ch = wid & 1;
    int arow = rg * 16 + (lane & 15);
    int koff = (lane >> 4) << 3;

    f32x4 acc[4];
#pragma unroll
    for (int nf = 0; nf < 4; ++nf) acc[nf] = (f32x4){0.f, 0.f, 0.f, 0.f};

#pragma unroll
    for (int ks = 0; ks < 8; ++ks) {
        short8 a = *reinterpret_cast<const short8*>(&xm[arow][ks * 32 + koff]);
#pragma unroll
        for (int nf = 0; nf < 4; ++nf) {
            int f = ks * 8 + ch * 4 + nf;
            short8 b = *reinterpret_cast<const short8*>(w_swz + (((size_t)f * 64 + lane) << 3));
            acc[nf] = __builtin_amdgcn_mfma_f32_16x16x32_bf16(a, b, acc[nf], 0, 0, 0);
        }
    }

    int crow0 = rg * 16 + ((lane >> 4) << 2);
#pragma unroll
    for (int nf = 0; nf < 4; ++nf) {
        int col = (ch * 4 + nf) * 16 + (lane & 15);
        float bs = bias[col];
#pragma unroll
        for (int r = 0; r < 4; ++r) {
            int grow = gbase + crow0 + r;
            if (grow < n) out[(size_t)grow * DIM + col] = acc[nf][r] + bs;
        }
    }
}

extern "C" void kernel_launch(void* const* d_in, const int* in_sizes, int n_in,
                              void* d_out, int out_size, void* d_ws, size_t ws_size,
                              hipStream_t stream) {
    const float* x       = (const float*)d_in[0];
    const int*   ei      = (const int*)d_in[1];
    const float* w_self  = (const float*)d_in[2];
    const float* b_self  = (const float*)d_in[3];
    const float* w_neigh = (const float*)d_in[4];
    const float* b_neigh = (const float*)d_in[5];
    float* out = (float*)d_out;

    int n = in_sizes[0] / DIM;
    int E = in_sizes[1] / 2;
    int NB = (n + BUCK - 1) / BUCK;   // 1563 for n=50000; requires NB <= NBMAX

    // ws: gcur[NBMAX] | ovfc[4] | csr uint[NB*CAPB] (~6.4MB) | ovf uint[E] (~3.2MB) |
    //     (align16) w_swz bf16[32768] | bias f32[128] | x_bf bf16[n*128] (~12.8MB) |
    //     x_fp8 uint[n*32] (~6.4MB)
    int* gcur = (int*)d_ws;
    int* ovfc = gcur + NBMAX;
    unsigned int* csr = (unsigned int*)(ovfc + 4);
    unsigned int* ovf = csr + (size_t)NB * CAPB;
    unsigned short* w_swz = (unsigned short*)(((uintptr_t)(ovf + E) + 15) & ~(uintptr_t)15);
    float* bias = (float*)(w_swz + 64 * 64 * 8);
    unsigned short* x_bf = (unsigned short*)(bias + 128);
    unsigned int* x_fp8 = (unsigned int*)(x_bf + (size_t)n * DIM);

    hipMemsetAsync(gcur, 0, (NBMAX + 4) * sizeof(int), stream);

    int n4 = n * DIM / 4;
    int PBLKS = (E + PCH - 1) / PCH;   // 196
    setup_partition_kernel<<<PBLKS + CONV_BLKS + WPACK_BLKS, NT, 0, stream>>>(
        x, ei, w_self, b_self, w_neigh, b_neigh, x_bf, x_fp8, w_swz, bias,
        gcur, ovfc, csr, ovf, n4, E, NB, PBLKS);

    fused_aggregate_kernel<<<NB, BAT, 0, stream>>>(x_bf, x_fp8, gcur, ovfc, csr, ovf,
                                                   w_swz, bias, out, n);
}

// Round 16
// 66.238 us; speedup vs baseline: 1.4603x; 1.1191x over previous
//
#include <hip/hip_runtime.h>

#define DIM 128
#define BUCK 16          // dst nodes per bucket == MFMA tile rows
#define PCH 8192         // edges per partition chunk
#define NBMAX 4096       // max buckets (n <= 65536)
#define BAT 128          // threads in fused aggregate (2 waves x 8 nodes)
#define CAPB 512         // fixed csr slots per bucket (avg 256, max ~360; overflow-safe)
#define NTS 512          // setup kernel block size
#define CONV_BLKS 256
#define WPACK_BLKS 8

typedef __attribute__((ext_vector_type(8))) short short8;
typedef __attribute__((ext_vector_type(8))) unsigned short ushort8;
typedef __attribute__((ext_vector_type(4))) float f32x4;
typedef __attribute__((ext_vector_type(2))) float f32x2;

static __device__ __forceinline__ unsigned short f32_to_bf16(float f) {
    union { float f; unsigned int u; } c; c.f = f;
    unsigned int u = c.u;
    u += 0x7FFFu + ((u >> 16) & 1u);   // RNE
    return (unsigned short)(u >> 16);
}

// ONE setup kernel (512 threads), three independent block roles:
//  [0, PBLKS):            chunk-local partition into fixed-capacity bucket regions
//  [PBLKS, +CONV_BLKS):   x f32 -> bf16 table AND fp8(e4m3) gather table
//  [+, +WPACK_BLKS):      weight pack (MFMA B-fragment order) + combined bias
__global__ void __launch_bounds__(NTS)
setup_partition_kernel(const float* __restrict__ x, const int* __restrict__ ei,
                       const float* __restrict__ w_self, const float* __restrict__ b_self,
                       const float* __restrict__ w_neigh, const float* __restrict__ b_neigh,
                       unsigned short* __restrict__ xb, unsigned int* __restrict__ xf8,
                       unsigned short* __restrict__ w_swz,
                       float* __restrict__ bias, int* __restrict__ gcur,
                       int* __restrict__ ovfc, unsigned int* __restrict__ csr,
                       unsigned int* __restrict__ ovf,
                       int n4, int E, int NB, int PBLKS) {
    int b = blockIdx.x, t = threadIdx.x;
    if (b < PBLKS) {
        __shared__ int hist[NBMAX];            // pass 1: counts; pass 2: local cursor
        __shared__ unsigned int bav[NBMAX];    // packed base<<16 | avail
        int cbase = b * PCH;
        int cend = min(E, cbase + PCH);
        for (int i = t; i < NB; i += NTS) hist[i] = 0;
        __syncthreads();
        for (int e = cbase + t; e < cend; e += NTS)
            atomicAdd(&hist[ei[E + e] >> 4], 1);
        __syncthreads();
        for (int bk = t; bk < NB; bk += NTS) {
            int c = hist[bk];
            unsigned int pack = 0;
            if (c) {
                int r = atomicAdd(&gcur[bk], c);
                int base = min(r, CAPB);
                int av = min(c, CAPB - base);
                pack = ((unsigned int)base << 16) | (unsigned int)av;
            }
            bav[bk] = pack;
            hist[bk] = 0;                      // becomes local cursor
        }
        __syncthreads();
        for (int e = cbase + t; e < cend; e += NTS) {
            unsigned int src = (unsigned int)ei[e];
            unsigned int dst = (unsigned int)ei[E + e];
            int bk = (int)(dst >> 4);
            int idx = atomicAdd(&hist[bk], 1);
            unsigned int pk = (dst << 16) | src;
            unsigned int pa = bav[bk];
            int base = (int)(pa >> 16), av = (int)(pa & 0xFFFFu);
            if (idx < av) csr[(size_t)bk * CAPB + base + idx] = pk;
            else ovf[atomicAdd(ovfc, 1)] = pk;   // rare
        }
    } else if (b < PBLKS + CONV_BLKS) {
        for (int g = (b - PBLKS) * NTS + t; g < n4; g += CONV_BLKS * NTS) {
            float4 v = reinterpret_cast<const float4*>(x)[g];
            ushort4 s = make_ushort4(f32_to_bf16(v.x), f32_to_bf16(v.y),
                                     f32_to_bf16(v.z), f32_to_bf16(v.w));
            reinterpret_cast<ushort4*>(xb)[g] = s;
            int p = __builtin_amdgcn_cvt_pk_fp8_f32(v.x, v.y, 0, false);   // bytes 0,1
            p = __builtin_amdgcn_cvt_pk_fp8_f32(v.z, v.w, p, true);        // bytes 2,3
            xf8[g] = (unsigned int)p;
        }
    } else {
        int g = (b - PBLKS - CONV_BLKS) * NTS + t;   // 4096 slots
        if (g < 128) bias[g] = b_self[g] + b_neigh[g];
        if (g >= 64 * 64) return;
        int f = g >> 6, l = g & 63;
        int ks = f >> 3, nf = f & 7;
        int j = nf * 16 + (l & 15);
        int kbase = ks * 32 + ((l >> 4) << 3);
#pragma unroll
        for (int e = 0; e < 8; ++e) {
            int k = kbase + e;
            float v = (k < 128) ? w_self[(size_t)j * 128 + k]
                                : w_neigh[(size_t)j * 128 + (k - 128)];
            w_swz[((size_t)g << 3) + e] = f32_to_bf16(v);
        }
    }
}

// FUSED aggregate + finalize. One block per 16-node bucket, 2 waves (~10KB LDS
// -> up to 16 blocks/CU; grid 3125 -> 12.2 blocks/CU for latency hiding).
// fp8 gather (R12-proven per-node form): one dwordx2 x 16 lanes covers a 128B
// row -> 4 edges/instr, 4 quad-loads (16 edges) in flight. 2 shfl_xor reduce,
// mean -> bf16 A-tile, 2-wave MFMA epilogue (wave = 16 rows x 64 cols).
__global__ void __launch_bounds__(BAT)
fused_aggregate_kernel(const unsigned short* __restrict__ xb,
                       const unsigned int* __restrict__ xf8,
                       const int* __restrict__ gcur,
                       const int* __restrict__ ovfc,
                       const unsigned int* __restrict__ csr,
                       const unsigned int* __restrict__ ovf,
                       const unsigned short* __restrict__ w_swz,
                       const float* __restrict__ bias,
                       float* __restrict__ out, int n) {
    __shared__ unsigned short srt[CAPB];       // sorted src ids (1KB)
    __shared__ unsigned short xm[BUCK][264];   // [x(128) | mean(128)] bf16 (8.25KB)
    __shared__ int bin[BUCK];
    __shared__ int boff_s[BUCK + 1];
    __shared__ int cur[BUCK];

    int tid = threadIdx.x, wid = tid >> 6, lane = tid & 63;
    int grp = lane >> 4, j = lane & 15;     // 4 groups of 16 lanes
    int b0 = blockIdx.x;
    int bsize = min(gcur[b0], CAPB);
    int ovfn = ovfc[0];
    const unsigned int* my = csr + (size_t)b0 * CAPB;
    int gbase = b0 * BUCK;
    const uint2* x8 = reinterpret_cast<const uint2*>(xf8);   // 16 uint2 per fp8 row

    // Stage x rows into A-tile x-part (coalesced, bf16).
    for (int fi = tid; fi < BUCK * 16; fi += BAT) {
        int row = fi >> 4, c = fi & 15;
        int grow = gbase + row;
        ushort8 s = (ushort8)0;
        if (grow < n) s = reinterpret_cast<const ushort8*>(xb + (size_t)grow * DIM)[c];
        *reinterpret_cast<ushort8*>(&xm[row][c * 8]) = s;
    }

    // ---- counting sort by local dst (16 bins) ----
    for (int i = tid; i < BUCK; i += BAT) bin[i] = 0;
    __syncthreads();
    for (int i = tid; i < bsize; i += BAT)
        atomicAdd(&bin[(my[i] >> 16) & 15], 1);
    __syncthreads();
    if (wid == 0) {   // lanes 0..15 scan 16 bins
        int v = (lane < BUCK) ? bin[lane] : 0;
        int s = v;
#pragma unroll
        for (int d = 1; d < BUCK; d <<= 1) {
            int u = __shfl_up(s, d, 64);
            if (lane >= d) s += u;
        }
        if (lane < BUCK) {
            boff_s[lane] = s - v;
            cur[lane] = s - v;
            if (lane == BUCK - 1) boff_s[BUCK] = s;
        }
    }
    __syncthreads();
    for (int i = tid; i < bsize; i += BAT) {
        unsigned int p = my[i];
        int d = (p >> 16) & 15;
        srt[atomicAdd(&cur[d], 1)] = (unsigned short)(p & 0xFFFFu);
    }
    __syncthreads();

    // ---- per-node gather (fp8), 4 edges/instr, 16 edges in flight ----
#pragma unroll 2
    for (int i = 0; i < 8; ++i) {
        int nd = wid * 8 + i;
        int s = boff_s[nd], epd = boff_s[nd + 1];
        f32x2 c0 = {0.f, 0.f}, c1 = {0.f, 0.f}, c2 = {0.f, 0.f}, c3 = {0.f, 0.f};
        for (int e = s; e < epd; e += 16) {
            uint2 v[4];
#pragma unroll
            for (int q = 0; q < 4; ++q) {
                int eidx = e + q * 4 + grp;
                bool ok = eidx < epd;
                uint2 tv = x8[(size_t)srt[ok ? eidx : s] * 16 + j];
                v[q] = ok ? tv : make_uint2(0u, 0u);
            }
#pragma unroll
            for (int q = 0; q < 4; ++q) {
                c0 += __builtin_amdgcn_cvt_pk_f32_fp8(v[q].x, false);
                c1 += __builtin_amdgcn_cvt_pk_f32_fp8(v[q].x, true);
                c2 += __builtin_amdgcn_cvt_pk_f32_fp8(v[q].y, false);
                c3 += __builtin_amdgcn_cvt_pk_f32_fp8(v[q].y, true);
            }
        }
        int deg = epd - s;
        // Overflow edges (normally ovfn == 0).
        for (int o = 0; o < ovfn; ++o) {
            unsigned int p = ovf[o];
            if ((int)(p >> 16) == gbase + nd) {
                uint2 tv = x8[(size_t)(p & 0xFFFFu) * 16 + j];
                c0 += __builtin_amdgcn_cvt_pk_f32_fp8(tv.x, false);
                c1 += __builtin_amdgcn_cvt_pk_f32_fp8(tv.x, true);
                c2 += __builtin_amdgcn_cvt_pk_f32_fp8(tv.y, false);
                c3 += __builtin_amdgcn_cvt_pk_f32_fp8(tv.y, true);
                ++deg;
            }
        }
        // cross-group reduce: sum the 4 lane-groups (same 8-col set each).
        float t[8] = {c0.x, c0.y, c1.x, c1.y, c2.x, c2.y, c3.x, c3.y};
#pragma unroll
        for (int k = 0; k < 8; ++k) {
            t[k] += __shfl_xor(t[k], 16);
            t[k] += __shfl_xor(t[k], 32);
        }
        float inv = deg > 0 ? 1.0f / (float)deg : 0.f;
        if (grp == 0) {
            ushort8 m = (ushort8)0;
#pragma unroll
            for (int k = 0; k < 8; ++k) m[k] = f32_to_bf16(t[k] * inv);
            *reinterpret_cast<ushort8*>(&xm[nd][128 + j * 8]) = m;
        }
    }
    __syncthreads();

    // ---- MFMA epilogue: 2 waves, wave = 16 rows x 64 cols ----
    int ch = wid;
    int arow = lane & 15;
    int koff = (lane >> 4) << 3;

    f32x4 acc[4];
#pragma unroll
    for (int nf = 0; nf < 4; ++nf) acc[nf] = (f32x4){0.f, 0.f, 0.f, 0.f};

#pragma unroll
    for (int ks = 0; ks < 8; ++ks) {
        short8 a = *reinterpret_cast<const short8*>(&xm[arow][ks * 32 + koff]);
#pragma unroll
        for (int nf = 0; nf < 4; ++nf) {
            int f = ks * 8 + ch * 4 + nf;
            short8 b = *reinterpret_cast<const short8*>(w_swz + (((size_t)f * 64 + lane) << 3));
            acc[nf] = __builtin_amdgcn_mfma_f32_16x16x32_bf16(a, b, acc[nf], 0, 0, 0);
        }
    }

    int crow0 = (lane >> 4) << 2;
#pragma unroll
    for (int nf = 0; nf < 4; ++nf) {
        int col = (ch * 4 + nf) * 16 + (lane & 15);
        float bs = bias[col];
#pragma unroll
        for (int r = 0; r < 4; ++r) {
            int grow = gbase + crow0 + r;
            if (grow < n) out[(size_t)grow * DIM + col] = acc[nf][r] + bs;
        }
    }
}

extern "C" void kernel_launch(void* const* d_in, const int* in_sizes, int n_in,
                              void* d_out, int out_size, void* d_ws, size_t ws_size,
                              hipStream_t stream) {
    const float* x       = (const float*)d_in[0];
    const int*   ei      = (const int*)d_in[1];
    const float* w_self  = (const float*)d_in[2];
    const float* b_self  = (const float*)d_in[3];
    const float* w_neigh = (const float*)d_in[4];
    const float* b_neigh = (const float*)d_in[5];
    float* out = (float*)d_out;

    int n = in_sizes[0] / DIM;
    int E = in_sizes[1] / 2;
    int NB = (n + BUCK - 1) / BUCK;   // 3125 for n=50000; requires NB <= NBMAX

    // ws: gcur[NBMAX] | ovfc[4] | csr uint[NB*CAPB] (~6.4MB) | ovf uint[E] (~3.2MB) |
    //     (align16) w_swz bf16[32768] | bias f32[128] | x_bf bf16[n*128] (~12.8MB) |
    //     x_fp8 uint[n*32] (~6.4MB)
    int* gcur = (int*)d_ws;
    int* ovfc = gcur + NBMAX;
    unsigned int* csr = (unsigned int*)(ovfc + 4);
    unsigned int* ovf = csr + (size_t)NB * CAPB;
    unsigned short* w_swz = (unsigned short*)(((uintptr_t)(ovf + E) + 15) & ~(uintptr_t)15);
    float* bias = (float*)(w_swz + 64 * 64 * 8);
    unsigned short* x_bf = (unsigned short*)(bias + 128);
    unsigned int* x_fp8 = (unsigned int*)(x_bf + (size_t)n * DIM);

    hipMemsetAsync(gcur, 0, (NBMAX + 4) * sizeof(int), stream);

    int n4 = n * DIM / 4;
    int PBLKS = (E + PCH - 1) / PCH;   // 98
    setup_partition_kernel<<<PBLKS + CONV_BLKS + WPACK_BLKS, NTS, 0, stream>>>(
        x, ei, w_self, b_self, w_neigh, b_neigh, x_bf, x_fp8, w_swz, bias,
        gcur, ovfc, csr, ovf, n4, E, NB, PBLKS);

    fused_aggregate_kernel<<<NB, BAT, 0, stream>>>(x_bf, x_fp8, gcur, ovfc, csr, ovf,
                                                   w_swz, bias, out, n);
}